// Round 9
// baseline (136.203 us; speedup 1.0000x reference)
//
#include <hip/hip_runtime.h>
#include <math.h>

#define SEQ   2048
#define DH    64
#define NBH   24
// scale * log2(e): softmax in exp2 domain
#define QSCALE 0.18033688011112042f

typedef __attribute__((ext_vector_type(8))) short short8;
typedef __attribute__((ext_vector_type(4))) short short4v;
typedef __attribute__((ext_vector_type(4))) float f32x4;

#define MFMA32(a, b, c) __builtin_amdgcn_mfma_f32_16x16x32_bf16((a), (b), (c), 0, 0, 0)
// gfx950 v_mfma_f32_16x16x16_bf16 (short4 operands) = the _1k builtin name.
#define MFMA16(a, b, c) __builtin_amdgcn_mfma_f32_16x16x16bf16_1k((a), (b), (c), 0, 0, 0)

// hardware RNE f32x2 -> packed bf16x2
__device__ __forceinline__ int cvtpk(float lo, float hi) {
    int r;
    asm("v_cvt_pk_bf16_f32 %0, %1, %2" : "=v"(r) : "v"(lo), "v"(hi));
    return r;
}

// ---- fused pre-pass, 32-row tiles, FRAGMENT-MAJOR outputs (unchanged R8 —
// this layout made every attn K/V load a dense 1KB wave segment and took
// attn 97 -> ~43us).
//   kb: per 16-seq block, 2KB chunk = two 1KB halves (d<32 | d>=32);
//       K[s][h*32 + quad*8 + r] at shorts[h*512 + (quad*16+(s&15))*8 + r].
//   vt: per (32-k-block, dt) 1KB chunk; lane(quad,l16) holds
//       V[k32+quad*4+i][dt*16+l16] (i<4) ++ V[k32+16+quad*4+i][...].
__global__ __launch_bounds__(256)
void cvt_all(const float* __restrict__ q, const float* __restrict__ k,
             const float* __restrict__ v,
             short* __restrict__ qb, short* __restrict__ kb,
             short* __restrict__ vt)
{
    __shared__ float tile[32][68];
    const int t  = threadIdx.x;
    const int bh = blockIdx.x;
    const int s0 = blockIdx.y * 32;
    const size_t base = ((size_t)bh * SEQ + s0) * DH;   // 32*64 f32 = 512 float4
    const size_t kbh  = (size_t)bh * SEQ * DH;

    #pragma unroll
    for (int i = 0; i < 2; ++i) {
        const int idx = i * 256 + t;
        float4 a = ((const float4*)(q + base))[idx];
        ((int2*)(qb + base))[idx] = make_int2(
            cvtpk(a.x * QSCALE, a.y * QSCALE),
            cvtpk(a.z * QSCALE, a.w * QSCALE));

        // K -> fragment-major
        float4 b = ((const float4*)(k + base))[idx];
        {
            const int sl   = idx >> 4;           // local row 0..31
            const int fgrp = idx & 15;           // float4-group = d0/4
            const int sblk = (s0 >> 4) + (sl >> 4);
            const int half = fgrp >> 3;
            const int quad = (fgrp >> 1) & 3;
            const int r04  = (fgrp & 1) * 4;
            short* p = kb + kbh + (size_t)sblk * 1024 + half * 512
                     + (quad * 16 + (sl & 15)) * 8 + r04;
            *(int2*)p = make_int2(cvtpk(b.x, b.y), cvtpk(b.z, b.w));
        }

        float4 c = ((const float4*)(v + base))[idx];
        const int sl = idx >> 4, cg = (idx & 15) * 4;
        *(float4*)(&tile[sl][cg]) = c;
    }
    __syncthreads();
    {
        const int dl = t >> 2;     // d index 0..63
        const int qq = t & 3;      // quarter within the 32-seq block
        float f[8];
        #pragma unroll
        for (int r = 0; r < 4; ++r) {
            f[r]     = tile[qq * 4 + r][dl];        // m=0 half
            f[4 + r] = tile[16 + qq * 4 + r][dl];   // m=1 half
        }
        short8 pc;
        ((int*)&pc)[0] = cvtpk(f[0], f[1]);
        ((int*)&pc)[1] = cvtpk(f[2], f[3]);
        ((int*)&pc)[2] = cvtpk(f[4], f[5]);
        ((int*)&pc)[3] = cvtpk(f[6], f[7]);
        // fragment-major: chunk (k32 = s0/32, dt = dl>>4), lane = qq*16+(dl&15)
        short* p = vt + kbh + (size_t)((s0 >> 5) * 4 + (dl >> 4)) * 512
                 + (qq * 16 + (dl & 15)) * 8;
        *(short8*)p = pc;
    }
}

// ---- main: SHARED-STREAM flash. R8 post-mortem: attn ~43us by gap
// arithmetic; remaining cost = 786MB L2->L1 traffic (each 32-row q-tile
// re-reads its K/V quarter) + L2 hit latency at 3 waves/SIMD. R9: drop
// split-K — block = 4 waves, each a DIFFERENT 32-row q-tile, all walking the
// SAME k-chunks in lockstep. Wave 0's miss fills L1 (32KB/CU, CU-shared);
// waves 1-3 hit L1 -> L2 traffic /4 (~200MB) and L1-hit latency. Raw
// s_barrier per iter (NOT __syncthreads: that drains vmcnt and would kill
// the K-prefetch; this barrier is scheduling-only — zero correctness
// dependence, G16-safe). Split-K merge epilogue deleted: each wave
// normalizes (fixed-frame l is complete per wave) and stores directly.
// No LDS at all. Grid 384 = 8 XCD x 48 (3 bh per XCD). Known trade:
// 1-2 waves/SIMD + 2-blocks on half the CUs — R7 proved TLP isn't binding,
// and 2-block CUs merely degenerate to R8 behavior.
__global__ __launch_bounds__(256, 3)
void attn_fwd(const short* __restrict__ qb, const short* __restrict__ kb,
              const short* __restrict__ vt, float* __restrict__ og)
{
    const int lane = threadIdx.x & 63;
    const int wave = threadIdx.x >> 6;     // q-subtile within the 128-row block
    const int quad = lane >> 4;
    const int l16  = lane & 15;
    const int lane8 = lane * 8;            // short offset of this lane's 16B

    // bijective XCD swizzle (384 = 8 XCD x 48): 3 bh per XCD
    const int swz = (blockIdx.x & 7) * 48 + (blockIdx.x >> 3);
    const int bh  = swz >> 4;                       // 16 blocks per bh
    const int q0  = (swz & 15) * 128 + wave * 32;   // this wave's q-rows

    const short* kbase = kb + (size_t)bh * SEQ * DH;
    const short* vbase = vt + (size_t)bh * DH * SEQ;

    short8 bq[2][2];
    #pragma unroll
    for (int qs = 0; qs < 2; ++qs) {
        const short* qrow = qb + ((size_t)(bh * SEQ + q0 + qs * 16 + l16)) * DH + quad * 8;
        bq[qs][0] = *(const short8*)(qrow);
        bq[qs][1] = *(const short8*)(qrow + 32);
    }

    f32x4 o[2][4];
    float l_i[2];
    #pragma unroll
    for (int qs = 0; qs < 2; ++qs) {
        l_i[qs] = 0.f;
        #pragma unroll
        for (int dt = 0; dt < 4; ++dt) o[qs][dt] = (f32x4){0.f, 0.f, 0.f, 0.f};
    }

    int k0 = 0;
    short8 ka[8];
    #pragma unroll
    for (int mt = 0; mt < 4; ++mt) {
        const short* kc = kbase + (size_t)mt * 1024 + lane8;
        ka[2 * mt]     = *(const short8*)(kc);
        ka[2 * mt + 1] = *(const short8*)(kc + 512);
    }

    #pragma unroll 1
    for (int iter = 0; iter < 32; ++iter, k0 += 64) {
        // lockstep barrier: keeps the 4 waves' identical loads within L1
        // line lifetime (scheduling-only; no waitcnt attached).
        __builtin_amdgcn_s_barrier();

        // ---- V(i) loads first: dense 1KB segments, covered by QK^T+exp2
        short8 av[2][4];
        #pragma unroll
        for (int pair = 0; pair < 2; ++pair)
            #pragma unroll
            for (int dt = 0; dt < 4; ++dt)
                av[pair][dt] = *(const short8*)(vbase
                    + (size_t)((((k0 >> 5) + pair) * 4) + dt) * 512 + lane8);

        short4v pb[2][4];

        // ---- per q-subtile: S^T = K @ Q^T then fixed-frame exp2+pack
        #pragma unroll
        for (int qs = 0; qs < 2; ++qs) {
            f32x4 c[4];
            __builtin_amdgcn_s_setprio(1);
            #pragma unroll
            for (int mt = 0; mt < 4; ++mt) {
                f32x4 z = (f32x4){0.f, 0.f, 0.f, 0.f};
                z = MFMA32(ka[2 * mt],     bq[qs][0], z);
                z = MFMA32(ka[2 * mt + 1], bq[qs][1], z);
                c[mt] = z;
            }
            __builtin_amdgcn_s_setprio(0);

            // K(i+1) prefetch right after ka's last use (qs==1 QK^T)
            if (qs == 1 && iter < 31) {
                const int k0n = k0 + 64;
                #pragma unroll
                for (int mt = 0; mt < 4; ++mt) {
                    const short* kc = kbase + (size_t)((k0n >> 4) + mt) * 1024 + lane8;
                    ka[2 * mt]     = *(const short8*)(kc);
                    ka[2 * mt + 1] = *(const short8*)(kc + 512);
                }
            }

            // p = exp2(S) raw — fixed frame; cancels in (Sum p*v)/(Sum p).
            float rsm[4];
            #pragma unroll
            for (int mt = 0; mt < 4; ++mt) {
                float p[4];
                #pragma unroll
                for (int r = 0; r < 4; ++r)
                    p[r] = __builtin_amdgcn_exp2f(c[mt][r]);
                rsm[mt] = (p[0] + p[1]) + (p[2] + p[3]);
                int2 w = make_int2(cvtpk(p[0], p[1]), cvtpk(p[2], p[3]));
                pb[qs][mt] = __builtin_bit_cast(short4v, w);
            }
            l_i[qs] += (rsm[0] + rsm[1]) + (rsm[2] + rsm[3]);
        }

        // ---- PV: shuffle-free, av already resident
        __builtin_amdgcn_s_setprio(1);
        #pragma unroll
        for (int pair = 0; pair < 2; ++pair) {
            #pragma unroll
            for (int dt = 0; dt < 4; ++dt) {
                const short4v alo = __builtin_shufflevector(av[pair][dt], av[pair][dt], 0, 1, 2, 3);
                const short4v ahi = __builtin_shufflevector(av[pair][dt], av[pair][dt], 4, 5, 6, 7);
                #pragma unroll
                for (int qs = 0; qs < 2; ++qs) {
                    o[qs][dt] = MFMA16(alo, pb[qs][2 * pair],     o[qs][dt]);
                    o[qs][dt] = MFMA16(ahi, pb[qs][2 * pair + 1], o[qs][dt]);
                }
            }
        }
        __builtin_amdgcn_s_setprio(0);
    }

    // ---- epilogue: no merge (full-K per wave). Cross-quad l reduce,
    // normalize, store directly.
    #pragma unroll
    for (int qs = 0; qs < 2; ++qs) {
        float l = l_i[qs];
        l += __shfl_xor(l, 16, 64);
        l += __shfl_xor(l, 32, 64);
        const float linv = 1.0f / l;
        float* orow = og + ((size_t)(bh * SEQ + q0 + qs * 16 + l16)) * DH;
        #pragma unroll
        for (int dt = 0; dt < 4; ++dt) {
            f32x4 st;
            #pragma unroll
            for (int r = 0; r < 4; ++r) st[r] = o[qs][dt][r] * linv;
            *(f32x4*)(orow + dt * 16 + quad * 4) = st;
        }
    }
}

extern "C" void kernel_launch(void* const* d_in, const int* in_sizes, int n_in,
                              void* d_out, int out_size, void* d_ws, size_t ws_size,
                              hipStream_t stream)
{
    const float* q = (const float*)d_in[0];
    const float* k = (const float*)d_in[1];
    const float* v = (const float*)d_in[2];
    float* o = (float*)d_out;

    const size_t nelem = (size_t)NBH * SEQ * DH;
    short* qb  = (short*)d_ws;
    short* kbp = qb + nelem;
    short* vtp = kbp + nelem;   // 18.9 MB total

    cvt_all<<<dim3(NBH, SEQ / 32), 256, 0, stream>>>(q, k, v, qb, kbp, vtp);
    attn_fwd<<<dim3(NBH * (SEQ / 128) * (128 / 128) * 16 / 16), 256, 0, stream>>>(qb, kbp, vtp, o);
    // grid = 24 bh x 16 q-tiles of 128 rows = 384 blocks
}

// Round 10
// 115.628 us; speedup vs baseline: 1.1779x; 1.1779x over previous
//
#include <hip/hip_runtime.h>
#include <math.h>

#define SEQ   2048
#define DH    64
#define NBH   24
// scale * log2(e): softmax in exp2 domain
#define QSCALE 0.18033688011112042f

typedef __attribute__((ext_vector_type(8))) short short8;
typedef __attribute__((ext_vector_type(4))) short short4v;
typedef __attribute__((ext_vector_type(4))) float f32x4;

#define MFMA32(a, b, c) __builtin_amdgcn_mfma_f32_16x16x32_bf16((a), (b), (c), 0, 0, 0)
// gfx950 v_mfma_f32_16x16x16_bf16 (short4 operands) = the _1k builtin name.
#define MFMA16(a, b, c) __builtin_amdgcn_mfma_f32_16x16x16bf16_1k((a), (b), (c), 0, 0, 0)

// hardware RNE f32x2 -> packed bf16x2
__device__ __forceinline__ int cvtpk(float lo, float hi) {
    int r;
    asm("v_cvt_pk_bf16_f32 %0, %1, %2" : "=v"(r) : "v"(lo), "v"(hi));
    return r;
}

// ---- fused pre-pass, 32-row tiles, FRAGMENT-MAJOR outputs (unchanged R8 —
// this layout made every attn K/V load a dense 1KB wave segment, 97->43us).
//   kb: per 16-seq block, 2KB chunk = two 1KB halves (d<32 | d>=32);
//       K[s][h*32 + quad*8 + r] at shorts[h*512 + (quad*16+(s&15))*8 + r].
//   vt: per (32-k-block, dt) 1KB chunk; lane(quad,l16) holds
//       V[k32+quad*4+i][dt*16+l16] (i<4) ++ V[k32+16+quad*4+i][...].
__global__ __launch_bounds__(256)
void cvt_all(const float* __restrict__ q, const float* __restrict__ k,
             const float* __restrict__ v,
             short* __restrict__ qb, short* __restrict__ kb,
             short* __restrict__ vt)
{
    __shared__ float tile[32][68];
    const int t  = threadIdx.x;
    const int bh = blockIdx.x;
    const int s0 = blockIdx.y * 32;
    const size_t base = ((size_t)bh * SEQ + s0) * DH;   // 32*64 f32 = 512 float4
    const size_t kbh  = (size_t)bh * SEQ * DH;

    #pragma unroll
    for (int i = 0; i < 2; ++i) {
        const int idx = i * 256 + t;
        float4 a = ((const float4*)(q + base))[idx];
        ((int2*)(qb + base))[idx] = make_int2(
            cvtpk(a.x * QSCALE, a.y * QSCALE),
            cvtpk(a.z * QSCALE, a.w * QSCALE));

        // K -> fragment-major
        float4 b = ((const float4*)(k + base))[idx];
        {
            const int sl   = idx >> 4;           // local row 0..31
            const int fgrp = idx & 15;           // float4-group = d0/4
            const int sblk = (s0 >> 4) + (sl >> 4);
            const int half = fgrp >> 3;
            const int quad = (fgrp >> 1) & 3;
            const int r04  = (fgrp & 1) * 4;
            short* p = kb + kbh + (size_t)sblk * 1024 + half * 512
                     + (quad * 16 + (sl & 15)) * 8 + r04;
            *(int2*)p = make_int2(cvtpk(b.x, b.y), cvtpk(b.z, b.w));
        }

        float4 c = ((const float4*)(v + base))[idx];
        const int sl = idx >> 4, cg = (idx & 15) * 4;
        *(float4*)(&tile[sl][cg]) = c;
    }
    __syncthreads();
    {
        const int dl = t >> 2;     // d index 0..63
        const int qq = t & 3;      // quarter within the 32-seq block
        float f[8];
        #pragma unroll
        for (int r = 0; r < 4; ++r) {
            f[r]     = tile[qq * 4 + r][dl];        // m=0 half
            f[4 + r] = tile[16 + qq * 4 + r][dl];   // m=1 half
        }
        short8 pc;
        ((int*)&pc)[0] = cvtpk(f[0], f[1]);
        ((int*)&pc)[1] = cvtpk(f[2], f[3]);
        ((int*)&pc)[2] = cvtpk(f[4], f[5]);
        ((int*)&pc)[3] = cvtpk(f[6], f[7]);
        // fragment-major: chunk (k32 = s0/32, dt = dl>>4), lane = qq*16+(dl&15)
        short* p = vt + kbh + (size_t)((s0 >> 5) * 4 + (dl >> 4)) * 512
                 + (qq * 16 + (dl & 15)) * 8;
        *(short8*)p = pc;
    }
}

// ---- main: 4-way split-K flash, 64 q-rows/wave. R9 post-mortem: aggregate
// L2 BW is NOT the limit (4x traffic cut made it slower — TLP collapse +
// grid imbalance dominated). Surviving theory: per-CU L2->L1 port traffic
// (R8: 786MB/256CU = 3.1MB/CU at ~64B/cy -> ~23us floor). R10: keep R8's
// proven structure (split-K 4, fragment-major dense loads, fixed-frame
// softmax, V-hoist, K-prefetch after last use) but 64 q-rows/wave: same K/V
// bytes amortized over 2x compute -> port traffic halves (393MB), and
// compute:load per iter doubles. PV moved inside the qs loop (pb transient,
// 8 regs) to fit: o64+bq32+ka32+av32+c16+pb8+temps ~ 195 < 256 cap (256,2).
// Grid 768 = 8 XCD x 96, balanced 3 blocks/CU (2 resident at a time).
// Pre-committed: WRITE>14MB = spill -> revert; attn >=40us = theory wrong.
__global__ __launch_bounds__(256, 2)
void attn_fwd(const short* __restrict__ qb, const short* __restrict__ kb,
              const short* __restrict__ vt, float* __restrict__ og)
{
    __shared__ float lds_o[4][4][64][17];   // [wave][qs][lane][16] padded
    __shared__ float lds_l[4][4][16];

    const int lane = threadIdx.x & 63;
    const int wave = threadIdx.x >> 6;     // k-quarter 0..3
    const int quad = lane >> 4;
    const int l16  = lane & 15;
    const int lane8 = lane * 8;            // short offset of this lane's 16B

    // bijective XCD swizzle (768 = 8 XCD x 96): 3 bh per XCD
    const int swz = (blockIdx.x & 7) * 96 + (blockIdx.x >> 3);
    const int bh  = swz >> 5;              // 32 blocks per bh
    const int q0  = (swz & 31) * 64;       // 64 q-rows per block

    const short* kbase = kb + (size_t)bh * SEQ * DH;
    const short* vbase = vt + (size_t)bh * DH * SEQ;

    short8 bq[4][2];
    #pragma unroll
    for (int qs = 0; qs < 4; ++qs) {
        const short* qrow = qb + ((size_t)(bh * SEQ + q0 + qs * 16 + l16)) * DH + quad * 8;
        bq[qs][0] = *(const short8*)(qrow);
        bq[qs][1] = *(const short8*)(qrow + 32);
    }

    f32x4 o[4][4];
    float l_i[4];
    #pragma unroll
    for (int qs = 0; qs < 4; ++qs) {
        l_i[qs] = 0.f;
        #pragma unroll
        for (int dt = 0; dt < 4; ++dt) o[qs][dt] = (f32x4){0.f, 0.f, 0.f, 0.f};
    }

    int k0 = wave * (SEQ / 4);
    short8 ka[8];
    #pragma unroll
    for (int mt = 0; mt < 4; ++mt) {
        const short* kc = kbase + (size_t)((k0 >> 4) + mt) * 1024 + lane8;
        ka[2 * mt]     = *(const short8*)(kc);
        ka[2 * mt + 1] = *(const short8*)(kc + 512);
    }

    #pragma unroll 1
    for (int iter = 0; iter < 8; ++iter, k0 += 64) {
        // ---- V(i) loads first: dense 1KB segments
        short8 av[2][4];
        #pragma unroll
        for (int pair = 0; pair < 2; ++pair)
            #pragma unroll
            for (int dt = 0; dt < 4; ++dt)
                av[pair][dt] = *(const short8*)(vbase
                    + (size_t)((((k0 >> 5) + pair) * 4) + dt) * 512 + lane8);

        // ---- per q-subtile: QK^T -> fixed-frame exp2+pack -> PV (pb transient)
        #pragma unroll
        for (int qs = 0; qs < 4; ++qs) {
            f32x4 c[4];
            __builtin_amdgcn_s_setprio(1);
            #pragma unroll
            for (int mt = 0; mt < 4; ++mt) {
                f32x4 z = (f32x4){0.f, 0.f, 0.f, 0.f};
                z = MFMA32(ka[2 * mt],     bq[qs][0], z);
                z = MFMA32(ka[2 * mt + 1], bq[qs][1], z);
                c[mt] = z;
            }
            __builtin_amdgcn_s_setprio(0);

            // K(i+1) prefetch right after ka's last use (qs==3 QK^T)
            if (qs == 3 && iter < 7) {
                const int k0n = k0 + 64;
                #pragma unroll
                for (int mt = 0; mt < 4; ++mt) {
                    const short* kc = kbase + (size_t)((k0n >> 4) + mt) * 1024 + lane8;
                    ka[2 * mt]     = *(const short8*)(kc);
                    ka[2 * mt + 1] = *(const short8*)(kc + 512);
                }
            }

            // p = exp2(S) raw — fixed frame; cancels in (Sum p*v)/(Sum p).
            short4v pb[4];
            float rsm[4];
            #pragma unroll
            for (int mt = 0; mt < 4; ++mt) {
                float p[4];
                #pragma unroll
                for (int r = 0; r < 4; ++r)
                    p[r] = __builtin_amdgcn_exp2f(c[mt][r]);
                rsm[mt] = (p[0] + p[1]) + (p[2] + p[3]);
                int2 w = make_int2(cvtpk(p[0], p[1]), cvtpk(p[2], p[3]));
                pb[mt] = __builtin_bit_cast(short4v, w);
            }
            l_i[qs] += (rsm[0] + rsm[1]) + (rsm[2] + rsm[3]);

            // PV for this qs (av resident since iter top)
            __builtin_amdgcn_s_setprio(1);
            #pragma unroll
            for (int pair = 0; pair < 2; ++pair) {
                #pragma unroll
                for (int dt = 0; dt < 4; ++dt) {
                    const short4v alo = __builtin_shufflevector(av[pair][dt], av[pair][dt], 0, 1, 2, 3);
                    const short4v ahi = __builtin_shufflevector(av[pair][dt], av[pair][dt], 4, 5, 6, 7);
                    o[qs][dt] = MFMA16(alo, pb[2 * pair],     o[qs][dt]);
                    o[qs][dt] = MFMA16(ahi, pb[2 * pair + 1], o[qs][dt]);
                }
            }
            __builtin_amdgcn_s_setprio(0);
        }
    }

    // ---- finalize per-row l (cross-quad) once
    #pragma unroll
    for (int qs = 0; qs < 4; ++qs) {
        float l = l_i[qs];
        l += __shfl_xor(l, 16, 64);
        l += __shfl_xor(l, 32, 64);
        l_i[qs] = l;
    }

    // ---- 4-way cross-wave merge: all waves write partials; each wave
    // combines 4 of the 16 (qs,dt) slices.
    #pragma unroll
    for (int qs = 0; qs < 4; ++qs) {
        #pragma unroll
        for (int dt = 0; dt < 4; ++dt)
            #pragma unroll
            for (int r = 0; r < 4; ++r)
                lds_o[wave][qs][lane][dt * 4 + r] = o[qs][dt][r];
        if (quad == 0) lds_l[wave][qs][l16] = l_i[qs];
    }
    __syncthreads();
    #pragma unroll
    for (int j = 0; j < 4; ++j) {
        const int s  = wave * 4 + j;
        const int qs = s >> 2, dt = s & 3;
        const float L = (lds_l[0][qs][l16] + lds_l[1][qs][l16])
                      + (lds_l[2][qs][l16] + lds_l[3][qs][l16]);
        const float linv = 1.0f / L;
        f32x4 st;
        #pragma unroll
        for (int r = 0; r < 4; ++r)
            st[r] = ((lds_o[0][qs][lane][dt * 4 + r] + lds_o[1][qs][lane][dt * 4 + r])
                   + (lds_o[2][qs][lane][dt * 4 + r] + lds_o[3][qs][lane][dt * 4 + r]))
                  * linv;
        *(f32x4*)(og + ((size_t)(bh * SEQ + q0 + qs * 16 + l16)) * DH
                  + dt * 16 + quad * 4) = st;
    }
}

extern "C" void kernel_launch(void* const* d_in, const int* in_sizes, int n_in,
                              void* d_out, int out_size, void* d_ws, size_t ws_size,
                              hipStream_t stream)
{
    const float* q = (const float*)d_in[0];
    const float* k = (const float*)d_in[1];
    const float* v = (const float*)d_in[2];
    float* o = (float*)d_out;

    const size_t nelem = (size_t)NBH * SEQ * DH;
    short* qb  = (short*)d_ws;
    short* kbp = qb + nelem;
    short* vtp = kbp + nelem;   // 18.9 MB total

    cvt_all<<<dim3(NBH, SEQ / 32), 256, 0, stream>>>(q, k, v, qb, kbp, vtp);
    attn_fwd<<<dim3(NBH * (SEQ / 64)), 256, 0, stream>>>(qb, kbp, vtp, o);
    // grid = 24 bh x 32 q-tiles of 64 rows = 768 blocks
}